// Round 10
// baseline (239.400 us; speedup 1.0000x reference)
//
#include <hip/hip_runtime.h>

// VQ-VAE VectorQuantizer2 forward for MI355X (gfx950)
// z:   (8, 8, 32, 32, 32) fp32  [b, c, l, h, w], c = e_dim = 8
// emb: (1024, 8) fp32
// out: [ z_q (2097152) | loss (1) | unique (1) | idx (262144) ]  all as fp32
//
// R8: register-block P=4 positions/thread to amortize per-code loads and
// any float4->VGPR materialization junk (R8 counters: busy-time 97us vs
// 44us 13-op model => ~28 eff ops/iter). d-arithmetic per position is
// UNCHANGED (idx passed bit-exact in R8; do not touch the FMA chain).
//
// ws layout (bytes):
//   [0,    4096)  used[1024]  int    (zeroed by vq_prep each launch)
//   [4096, 8192)  e2g[1024]   float  (||e_i||^2, by vq_prep)
//   [8192, 9216)  partials[256] float (per-block loss sums)

#define NE 1024
#define ED 8
#define NPOS 262144        // 8 * 32*32*32
#define SPAT 32768         // 32*32*32
#define CH_STRIDE 32768    // channel stride in floats
#define BATCH_STRIDE 262144// batch stride in floats (8 channels * 32768)
#define LOSS_OFF 2097152
#define UNIQ_OFF 2097153
#define IDX_OFF 2097154
#define PPT 4              // positions per thread
#define TQ 65536           // NPOS / PPT (position stride between the P slots)

__global__ __launch_bounds__(256)
void vq_prep(const float* __restrict__ emb, int* __restrict__ used,
             float* __restrict__ e2g) {
    int j = blockIdx.x * 256 + threadIdx.x;
    if (j < NE) {
        used[j] = 0;
        const float* e = emb + j * ED;
        float s;
        {
            // mul-then-add, no contraction (mirror elementwise-square+reduce)
            #pragma clang fp contract(off)
            float acc = e[0] * e[0];
            #pragma unroll
            for (int k = 1; k < ED; ++k) acc += e[k] * e[k];
            s = acc;
        }
        e2g[j] = s;
    }
}

__global__ __launch_bounds__(256)
void vq_main(const float* __restrict__ z, const float* __restrict__ emb,
             const float* __restrict__ e2g, float* __restrict__ out,
             int* __restrict__ used, float* __restrict__ partials) {
    const int tid = threadIdx.x;
    const int t0 = blockIdx.x * 256 + tid;   // 0..65535

    // Load PPT positions' vectors; static indexing throughout (rule #20).
    float zv[PPT][ED];
    float z2[PPT];
    #pragma unroll
    for (int p = 0; p < PPT; ++p) {
        const int n = t0 + p * TQ;
        const int b = n >> 15;              // n / SPAT
        const int s = n & (SPAT - 1);
        const float* zp = z + b * BATCH_STRIDE + s;
        #pragma unroll
        for (int c = 0; c < ED; ++c) zv[p][c] = zp[c * CH_STRIDE];
        {
            #pragma clang fp contract(off)
            float acc = zv[p][0] * zv[p][0];
            #pragma unroll
            for (int c = 1; c < ED; ++c) acc += zv[p][c] * zv[p][c];
            z2[p] = acc;
        }
    }

    const float4* cb4 = (const float4*)emb;
    float best0 = 3.4e38f, best1 = 3.4e38f, best2 = 3.4e38f, best3 = 3.4e38f;
    int bi0 = 0, bi1 = 0, bi2 = 0, bi3 = 0;

    // EXACT same per-position arithmetic as the R8-validated kernel:
    // sequential ascending-k FMA dot, d = fmaf(-2,dot,z2+e2), strict <.
    #define STEP(pp, bestv, biv)                                  \
        {                                                         \
            float dot = zv[pp][0] * ea.x;                         \
            dot = fmaf(zv[pp][1], ea.y, dot);                     \
            dot = fmaf(zv[pp][2], ea.z, dot);                     \
            dot = fmaf(zv[pp][3], ea.w, dot);                     \
            dot = fmaf(zv[pp][4], eb.x, dot);                     \
            dot = fmaf(zv[pp][5], eb.y, dot);                     \
            dot = fmaf(zv[pp][6], eb.z, dot);                     \
            dot = fmaf(zv[pp][7], eb.w, dot);                     \
            const float d = fmaf(-2.0f, dot, z2[pp] + e2);        \
            if (d < bestv) { bestv = d; biv = i; }                \
        }

    #pragma unroll 4
    for (int i = 0; i < NE; ++i) {
        const float4 ea = cb4[2 * i];
        const float4 eb = cb4[2 * i + 1];
        const float e2 = e2g[i];
        STEP(0, best0, bi0)
        STEP(1, best1, bi1)
        STEP(2, best2, bi2)
        STEP(3, best3, bi3)
    }
    #undef STEP

    // Epilogue per position: gather code, write z_q + idx, loss partial.
    float lacc = 0.0f;
    #define EPI(pp, biv)                                          \
        {                                                         \
            const int n = t0 + pp * TQ;                           \
            const int b = n >> 15;                                \
            const int s = n & (SPAT - 1);                         \
            const float4 wa = cb4[2 * biv];                       \
            const float4 wb = cb4[2 * biv + 1];                   \
            float ev[ED] = {wa.x, wa.y, wa.z, wa.w,               \
                            wb.x, wb.y, wb.z, wb.w};              \
            float* outq = out + b * BATCH_STRIDE + s;             \
            _Pragma("unroll")                                     \
            for (int c = 0; c < ED; ++c) {                        \
                const float diff = ev[c] - zv[pp][c];             \
                lacc = fmaf(diff, diff, lacc);                    \
                outq[c * CH_STRIDE] = ev[c];                      \
            }                                                     \
            out[IDX_OFF + n] = (float)biv;                        \
            used[biv] = 1;                                        \
        }

    EPI(0, bi0)
    EPI(1, bi1)
    EPI(2, bi2)
    EPI(3, bi3)
    #undef EPI

    // Deterministic block-tree reduction of loss partial (graph replay must
    // revalidate bit-identically -> no float atomics)
    __shared__ float red[256];
    red[tid] = lacc;
    __syncthreads();
    #pragma unroll
    for (int off = 128; off > 0; off >>= 1) {
        if (tid < off) red[tid] += red[tid + off];
        __syncthreads();
    }
    if (tid == 0) partials[blockIdx.x] = red[0];
}

__global__ __launch_bounds__(256)
void vq_final(const float* __restrict__ partials, const int* __restrict__ used,
              float* __restrict__ out) {
    __shared__ float sred[256];
    __shared__ int ured[256];
    const int t = threadIdx.x;
    sred[t] = partials[t];
    ured[t] = (used[t] ? 1 : 0) + (used[t + 256] ? 1 : 0)
            + (used[t + 512] ? 1 : 0) + (used[t + 768] ? 1 : 0);
    __syncthreads();
    for (int off = 128; off > 0; off >>= 1) {
        if (t < off) { sred[t] += sred[t + off]; ured[t] += ured[t + off]; }
        __syncthreads();
    }
    if (t == 0) {
        const float M = sred[0] * (1.0f / 2097152.0f);  // exact pow2 scale
        out[LOSS_OFF] = 0.25f * M + M;   // beta*mean + mean (forward values equal)
        out[UNIQ_OFF] = (float)ured[0];
    }
}

extern "C" void kernel_launch(void* const* d_in, const int* in_sizes, int n_in,
                              void* d_out, int out_size, void* d_ws, size_t ws_size,
                              hipStream_t stream) {
    const float* z   = (const float*)d_in[0];
    const float* emb = (const float*)d_in[1];
    float* out = (float*)d_out;

    int*   used     = (int*)d_ws;
    float* e2g      = (float*)((char*)d_ws + 4096);
    float* partials = (float*)((char*)d_ws + 8192);

    vq_prep<<<4, 256, 0, stream>>>(emb, used, e2g);
    vq_main<<<NPOS / (256 * PPT), 256, 0, stream>>>(z, emb, e2g, out, used, partials);
    vq_final<<<1, 256, 0, stream>>>(partials, used, out);
}

// Round 11
// 151.258 us; speedup vs baseline: 1.5827x; 1.5827x over previous
//
#include <hip/hip_runtime.h>

// VQ-VAE VectorQuantizer2 forward for MI355X (gfx950)
// z:   (8, 8, 32, 32, 32) fp32  [b, c, l, h, w], c = e_dim = 8
// emb: (1024, 8) fp32
// out: [ z_q (2097152) | loss (1) | unique (1) | idx (262144) ]  all as fp32
//
// R10 history: P=1 (R8): 125us, VALU-issue-bound at ~36 instr/pos-code.
// P=4 (R10): busy 55us (amortization works) but 180us total — serialized
// s_load codebook fetch stalls ~290cyc/iter at 1 wave/SIMD (Failure A).
// R11: keep P=4, stage codebook+norms in LDS; inner loop becomes uniform-
// address ds_read_b128 broadcast (conflict-free), lgkmcnt-pipelined.
// d-arithmetic per position is UNCHANGED (bit-exact idx validated R8/R10).
//
// ws layout (bytes):
//   [0,    4096)  used[1024]  int    (zeroed by vq_prep each launch)
//   [4096, 8192)  e2g[1024]   float  (||e_i||^2, by vq_prep)
//   [8192, 9216)  partials[256] float (per-block loss sums)

#define NE 1024
#define ED 8
#define NPOS 262144        // 8 * 32*32*32
#define SPAT 32768         // 32*32*32
#define CH_STRIDE 32768    // channel stride in floats
#define BATCH_STRIDE 262144// batch stride in floats (8 channels * 32768)
#define LOSS_OFF 2097152
#define UNIQ_OFF 2097153
#define IDX_OFF 2097154
#define PPT 4              // positions per thread
#define TQ 65536           // NPOS / PPT (position stride between the P slots)

__global__ __launch_bounds__(256)
void vq_prep(const float* __restrict__ emb, int* __restrict__ used,
             float* __restrict__ e2g) {
    int j = blockIdx.x * 256 + threadIdx.x;
    if (j < NE) {
        used[j] = 0;
        const float* e = emb + j * ED;
        float s;
        {
            // mul-then-add, no contraction (mirror elementwise-square+reduce)
            #pragma clang fp contract(off)
            float acc = e[0] * e[0];
            #pragma unroll
            for (int k = 1; k < ED; ++k) acc += e[k] * e[k];
            s = acc;
        }
        e2g[j] = s;
    }
}

__global__ __launch_bounds__(256)
void vq_main(const float* __restrict__ z, const float* __restrict__ emb,
             const float* __restrict__ e2g, float* __restrict__ out,
             int* __restrict__ used, float* __restrict__ partials) {
    const int tid = threadIdx.x;
    const int t0 = blockIdx.x * 256 + tid;   // 0..65535

    // --- Stage codebook (32 KB) + norms (4 KB) into LDS -----------------
    __shared__ float4 cbl[NE * 2];   // [2i]=code i floats 0..3, [2i+1]=4..7
    __shared__ float  e2l[NE];
    {
        const float4* cbg = (const float4*)emb;
        #pragma unroll
        for (int k = 0; k < 8; ++k) cbl[tid + k * 256] = cbg[tid + k * 256];
        #pragma unroll
        for (int k = 0; k < 4; ++k) e2l[tid + k * 256] = e2g[tid + k * 256];
    }

    // --- Load PPT positions' vectors (overlaps with staging) ------------
    float zv[PPT][ED];
    float z2[PPT];
    #pragma unroll
    for (int p = 0; p < PPT; ++p) {
        const int n = t0 + p * TQ;
        const int b = n >> 15;              // n / SPAT
        const int s = n & (SPAT - 1);
        const float* zp = z + b * BATCH_STRIDE + s;
        #pragma unroll
        for (int c = 0; c < ED; ++c) zv[p][c] = zp[c * CH_STRIDE];
        {
            #pragma clang fp contract(off)
            float acc = zv[p][0] * zv[p][0];
            #pragma unroll
            for (int c = 1; c < ED; ++c) acc += zv[p][c] * zv[p][c];
            z2[p] = acc;
        }
    }
    __syncthreads();

    float best0 = 3.4e38f, best1 = 3.4e38f, best2 = 3.4e38f, best3 = 3.4e38f;
    int bi0 = 0, bi1 = 0, bi2 = 0, bi3 = 0;

    // EXACT same per-position arithmetic as the R8-validated kernel:
    // sequential ascending-k FMA dot, d = fmaf(-2,dot,z2+e2), strict <.
    #define STEP(pp, bestv, biv)                                  \
        {                                                         \
            float dot = zv[pp][0] * ea.x;                         \
            dot = fmaf(zv[pp][1], ea.y, dot);                     \
            dot = fmaf(zv[pp][2], ea.z, dot);                     \
            dot = fmaf(zv[pp][3], ea.w, dot);                     \
            dot = fmaf(zv[pp][4], eb.x, dot);                     \
            dot = fmaf(zv[pp][5], eb.y, dot);                     \
            dot = fmaf(zv[pp][6], eb.z, dot);                     \
            dot = fmaf(zv[pp][7], eb.w, dot);                     \
            const float d = fmaf(-2.0f, dot, z2[pp] + e2);        \
            if (d < bestv) { bestv = d; biv = i; }                \
        }

    // Uniform-address LDS reads: broadcast, conflict-free, lgkmcnt-pipelined
    // with immediate offsets inside the unroll-4 group.
    #pragma unroll 4
    for (int i = 0; i < NE; ++i) {
        const float4 ea = cbl[2 * i];
        const float4 eb = cbl[2 * i + 1];
        const float e2 = e2l[i];
        STEP(0, best0, bi0)
        STEP(1, best1, bi1)
        STEP(2, best2, bi2)
        STEP(3, best3, bi3)
    }
    #undef STEP

    // Epilogue per position: gather code (global, L1/L2-hot; unchanged
    // validated path), write z_q + idx, loss partial.
    const float4* cb4 = (const float4*)emb;
    float lacc = 0.0f;
    #define EPI(pp, biv)                                          \
        {                                                         \
            const int n = t0 + pp * TQ;                           \
            const int b = n >> 15;                                \
            const int s = n & (SPAT - 1);                         \
            const float4 wa = cb4[2 * biv];                       \
            const float4 wb = cb4[2 * biv + 1];                   \
            float ev[ED] = {wa.x, wa.y, wa.z, wa.w,               \
                            wb.x, wb.y, wb.z, wb.w};              \
            float* outq = out + b * BATCH_STRIDE + s;             \
            _Pragma("unroll")                                     \
            for (int c = 0; c < ED; ++c) {                        \
                const float diff = ev[c] - zv[pp][c];             \
                lacc = fmaf(diff, diff, lacc);                    \
                outq[c * CH_STRIDE] = ev[c];                      \
            }                                                     \
            out[IDX_OFF + n] = (float)biv;                        \
            used[biv] = 1;                                        \
        }

    EPI(0, bi0)
    EPI(1, bi1)
    EPI(2, bi2)
    EPI(3, bi3)
    #undef EPI

    // Deterministic block-tree reduction of loss partial (graph replay must
    // revalidate bit-identically -> no float atomics)
    __shared__ float red[256];
    red[tid] = lacc;
    __syncthreads();
    #pragma unroll
    for (int off = 128; off > 0; off >>= 1) {
        if (tid < off) red[tid] += red[tid + off];
        __syncthreads();
    }
    if (tid == 0) partials[blockIdx.x] = red[0];
}

__global__ __launch_bounds__(256)
void vq_final(const float* __restrict__ partials, const int* __restrict__ used,
              float* __restrict__ out) {
    __shared__ float sred[256];
    __shared__ int ured[256];
    const int t = threadIdx.x;
    sred[t] = partials[t];
    ured[t] = (used[t] ? 1 : 0) + (used[t + 256] ? 1 : 0)
            + (used[t + 512] ? 1 : 0) + (used[t + 768] ? 1 : 0);
    __syncthreads();
    for (int off = 128; off > 0; off >>= 1) {
        if (t < off) { sred[t] += sred[t + off]; ured[t] += ured[t + off]; }
        __syncthreads();
    }
    if (t == 0) {
        const float M = sred[0] * (1.0f / 2097152.0f);  // exact pow2 scale
        out[LOSS_OFF] = 0.25f * M + M;   // beta*mean + mean (forward values equal)
        out[UNIQ_OFF] = (float)ured[0];
    }
}

extern "C" void kernel_launch(void* const* d_in, const int* in_sizes, int n_in,
                              void* d_out, int out_size, void* d_ws, size_t ws_size,
                              hipStream_t stream) {
    const float* z   = (const float*)d_in[0];
    const float* emb = (const float*)d_in[1];
    float* out = (float*)d_out;

    int*   used     = (int*)d_ws;
    float* e2g      = (float*)((char*)d_ws + 4096);
    float* partials = (float*)((char*)d_ws + 8192);

    vq_prep<<<4, 256, 0, stream>>>(emb, used, e2g);
    vq_main<<<NPOS / (256 * PPT), 256, 0, stream>>>(z, emb, e2g, out, used, partials);
    vq_final<<<1, 256, 0, stream>>>(partials, used, out);
}

// Round 12
// 150.579 us; speedup vs baseline: 1.5899x; 1.0045x over previous
//
#include <hip/hip_runtime.h>

// VQ-VAE VectorQuantizer2 forward for MI355X (gfx950)
// z:   (8, 8, 32, 32, 32) fp32  [b, c, l, h, w], c = e_dim = 8
// emb: (1024, 8) fp32
// out: [ z_q (2097152) | loss (1) | unique (1) | idx (262144) ]  all as fp32
//
// History: R8 P=1 s_load: 125us (VALU-issue-bound, ~36 instr/pos-code).
// R10 P=4 s_load: 180us (s_load serialized at 1 wave/SIMD). R11 P=4 LDS:
// 102us, VALUBusy 62% — ds_read first-use latency exposed at unroll-group
// boundaries (~136cyc stall/iter). R12: explicit A/B register double-buffer
// prefetch of the next 4-code group; compute on one buffer covers the
// other's ds_read latency. d-arithmetic UNCHANGED (bit-exact idx x3 rounds).
//
// ws layout (bytes):
//   [0,    4096)  used[1024]  int    (zeroed by vq_prep each launch)
//   [4096, 8192)  e2g[1024]   float  (||e_i||^2, by vq_prep)
//   [8192, 9216)  partials[256] float (per-block loss sums)

#define NE 1024
#define ED 8
#define NPOS 262144        // 8 * 32*32*32
#define SPAT 32768         // 32*32*32
#define CH_STRIDE 32768    // channel stride in floats
#define BATCH_STRIDE 262144// batch stride in floats (8 channels * 32768)
#define LOSS_OFF 2097152
#define UNIQ_OFF 2097153
#define IDX_OFF 2097154
#define PPT 4              // positions per thread
#define TQ 65536           // NPOS / PPT (position stride between the P slots)

__global__ __launch_bounds__(256)
void vq_prep(const float* __restrict__ emb, int* __restrict__ used,
             float* __restrict__ e2g) {
    int j = blockIdx.x * 256 + threadIdx.x;
    if (j < NE) {
        used[j] = 0;
        const float* e = emb + j * ED;
        float s;
        {
            // mul-then-add, no contraction (mirror elementwise-square+reduce)
            #pragma clang fp contract(off)
            float acc = e[0] * e[0];
            #pragma unroll
            for (int k = 1; k < ED; ++k) acc += e[k] * e[k];
            s = acc;
        }
        e2g[j] = s;
    }
}

__global__ __launch_bounds__(256)
void vq_main(const float* __restrict__ z, const float* __restrict__ emb,
             const float* __restrict__ e2g, float* __restrict__ out,
             int* __restrict__ used, float* __restrict__ partials) {
    const int tid = threadIdx.x;
    const int t0 = blockIdx.x * 256 + tid;   // 0..65535

    // --- Stage codebook (32 KB) + norms (4 KB) into LDS -----------------
    __shared__ float4 cbl[NE * 2];   // [2i]=code i floats 0..3, [2i+1]=4..7
    __shared__ float  e2l[NE];
    {
        const float4* cbg = (const float4*)emb;
        #pragma unroll
        for (int k = 0; k < 8; ++k) cbl[tid + k * 256] = cbg[tid + k * 256];
        #pragma unroll
        for (int k = 0; k < 4; ++k) e2l[tid + k * 256] = e2g[tid + k * 256];
    }

    // --- Load PPT positions' vectors (overlaps with staging) ------------
    float zv[PPT][ED];
    float z2[PPT];
    #pragma unroll
    for (int p = 0; p < PPT; ++p) {
        const int n = t0 + p * TQ;
        const int b = n >> 15;              // n / SPAT
        const int s = n & (SPAT - 1);
        const float* zp = z + b * BATCH_STRIDE + s;
        #pragma unroll
        for (int c = 0; c < ED; ++c) zv[p][c] = zp[c * CH_STRIDE];
        {
            #pragma clang fp contract(off)
            float acc = zv[p][0] * zv[p][0];
            #pragma unroll
            for (int c = 1; c < ED; ++c) acc += zv[p][c] * zv[p][c];
            z2[p] = acc;
        }
    }
    __syncthreads();

    float best0 = 3.4e38f, best1 = 3.4e38f, best2 = 3.4e38f, best3 = 3.4e38f;
    int bi0 = 0, bi1 = 0, bi2 = 0, bi3 = 0;

    // EXACT same per-position arithmetic as the R8-validated kernel:
    // sequential ascending-k FMA dot, d = fmaf(-2,dot,z2+e2), strict <.
    #define STEP(pp, bestv, biv)                                  \
        {                                                         \
            float dot = zv[pp][0] * ea.x;                         \
            dot = fmaf(zv[pp][1], ea.y, dot);                     \
            dot = fmaf(zv[pp][2], ea.z, dot);                     \
            dot = fmaf(zv[pp][3], ea.w, dot);                     \
            dot = fmaf(zv[pp][4], eb.x, dot);                     \
            dot = fmaf(zv[pp][5], eb.y, dot);                     \
            dot = fmaf(zv[pp][6], eb.z, dot);                     \
            dot = fmaf(zv[pp][7], eb.w, dot);                     \
            const float d = fmaf(-2.0f, dot, z2[pp] + e2);        \
            if (d < bestv) { bestv = d; biv = i; }                \
        }

    // Load group of 4 codes (36 floats) from LDS into named register buffer.
    #define LOADG(base, EA, EB, E2)                               \
        _Pragma("unroll")                                         \
        for (int k = 0; k < 4; ++k) {                             \
            EA[k] = cbl[2 * ((base) + k)];                        \
            EB[k] = cbl[2 * ((base) + k) + 1];                    \
            E2[k] = e2l[(base) + k];                              \
        }

    // Compute 4 codes x 4 positions from a register buffer.
    #define STEP4(EA, EB, E2, base)                               \
        _Pragma("unroll")                                         \
        for (int k = 0; k < 4; ++k) {                             \
            const float4 ea = EA[k];                              \
            const float4 eb = EB[k];                              \
            const float e2 = E2[k];                               \
            const int i = (base) + k;                             \
            STEP(0, best0, bi0)                                   \
            STEP(1, best1, bi1)                                   \
            STEP(2, best2, bi2)                                   \
            STEP(3, best3, bi3)                                   \
        }

    // Software pipeline: two named buffers (A,B), prefetch one group ahead.
    // ~208 VALU cyc per STEP4 covers ~120cyc ds_read first-use latency.
    float4 Aea[4], Aeb[4]; float Ae2[4];
    float4 Bea[4], Beb[4]; float Be2[4];
    LOADG(0, Aea, Aeb, Ae2)
    for (int i0 = 0; i0 < NE - 8; i0 += 8) {
        LOADG(i0 + 4, Bea, Beb, Be2)
        STEP4(Aea, Aeb, Ae2, i0)
        LOADG(i0 + 8, Aea, Aeb, Ae2)
        STEP4(Bea, Beb, Be2, i0 + 4)
    }
    // Tail: i0 = NE-8; A holds group for NE-8.
    LOADG(NE - 4, Bea, Beb, Be2)
    STEP4(Aea, Aeb, Ae2, NE - 8)
    STEP4(Bea, Beb, Be2, NE - 4)

    #undef STEP4
    #undef LOADG
    #undef STEP

    // Epilogue per position: gather code (global, L1/L2-hot; unchanged
    // validated path), write z_q + idx, loss partial.
    const float4* cb4 = (const float4*)emb;
    float lacc = 0.0f;
    #define EPI(pp, biv)                                          \
        {                                                         \
            const int n = t0 + pp * TQ;                           \
            const int b = n >> 15;                                \
            const int s = n & (SPAT - 1);                         \
            const float4 wa = cb4[2 * biv];                       \
            const float4 wb = cb4[2 * biv + 1];                   \
            float ev[ED] = {wa.x, wa.y, wa.z, wa.w,               \
                            wb.x, wb.y, wb.z, wb.w};              \
            float* outq = out + b * BATCH_STRIDE + s;             \
            _Pragma("unroll")                                     \
            for (int c = 0; c < ED; ++c) {                        \
                const float diff = ev[c] - zv[pp][c];             \
                lacc = fmaf(diff, diff, lacc);                    \
                outq[c * CH_STRIDE] = ev[c];                      \
            }                                                     \
            out[IDX_OFF + n] = (float)biv;                        \
            used[biv] = 1;                                        \
        }

    EPI(0, bi0)
    EPI(1, bi1)
    EPI(2, bi2)
    EPI(3, bi3)
    #undef EPI

    // Deterministic block-tree reduction of loss partial (graph replay must
    // revalidate bit-identically -> no float atomics)
    __shared__ float red[256];
    red[tid] = lacc;
    __syncthreads();
    #pragma unroll
    for (int off = 128; off > 0; off >>= 1) {
        if (tid < off) red[tid] += red[tid + off];
        __syncthreads();
    }
    if (tid == 0) partials[blockIdx.x] = red[0];
}

__global__ __launch_bounds__(256)
void vq_final(const float* __restrict__ partials, const int* __restrict__ used,
              float* __restrict__ out) {
    __shared__ float sred[256];
    __shared__ int ured[256];
    const int t = threadIdx.x;
    sred[t] = partials[t];
    ured[t] = (used[t] ? 1 : 0) + (used[t + 256] ? 1 : 0)
            + (used[t + 512] ? 1 : 0) + (used[t + 768] ? 1 : 0);
    __syncthreads();
    for (int off = 128; off > 0; off >>= 1) {
        if (t < off) { sred[t] += sred[t + off]; ured[t] += ured[t + off]; }
        __syncthreads();
    }
    if (t == 0) {
        const float M = sred[0] * (1.0f / 2097152.0f);  // exact pow2 scale
        out[LOSS_OFF] = 0.25f * M + M;   // beta*mean + mean (forward values equal)
        out[UNIQ_OFF] = (float)ured[0];
    }
}

extern "C" void kernel_launch(void* const* d_in, const int* in_sizes, int n_in,
                              void* d_out, int out_size, void* d_ws, size_t ws_size,
                              hipStream_t stream) {
    const float* z   = (const float*)d_in[0];
    const float* emb = (const float*)d_in[1];
    float* out = (float*)d_out;

    int*   used     = (int*)d_ws;
    float* e2g      = (float*)((char*)d_ws + 4096);
    float* partials = (float*)((char*)d_ws + 8192);

    vq_prep<<<4, 256, 0, stream>>>(emb, used, e2g);
    vq_main<<<NPOS / (256 * PPT), 256, 0, stream>>>(z, emb, e2g, out, used, partials);
    vq_final<<<1, 256, 0, stream>>>(partials, used, out);
}